// Round 3
// baseline (1443.920 us; speedup 1.0000x reference)
//
#include <hip/hip_runtime.h>
#include <hip/hip_bf16.h>

#define B_    32
#define S_    512
#define C_    16
#define DIN_  256
#define DOUT_ 64

// u_hat[b,c,s,o] = sum_i x[b,s,i] * W[c,s,i,o]   (all fp32)
// One wave per (c,s): lane = o, 32 fp32 accumulators (one per b).
// W row W[c,s,i,:] loaded once (coalesced 256B/wave) and reused across all 32 b.
// x[b,s,i0..i0+3] are wave-uniform float4 loads (L2/L3-resident, scalarizable).
// Epilogue fuses routing iter-0: s0[b,c,o] += u_hat/16 (softmax of zeros = 1/C).
__global__ __launch_bounds__(256) void gemm_uhat(
    const float* __restrict__ x, const float* __restrict__ W,
    float* __restrict__ u_hat, float* __restrict__ s_acc0) {
    const int lane = threadIdx.x & 63;
    const int wid  = threadIdx.x >> 6;
    const int s    = blockIdx.x >> 2;                 // 4 blocks per s
    const int c    = ((blockIdx.x & 3) << 2) + wid;   // 4 waves = 4 capsules, shared s -> x reuse

    const float* wp = W + (((size_t)c * S_ + s) * DIN_) * DOUT_ + lane;
    const float* xp = x + (size_t)s * DIN_;           // x[b,s,i] = xp[b*S*DIN + i]

    float acc[B_];
#pragma unroll
    for (int b = 0; b < B_; ++b) acc[b] = 0.f;

    for (int i0 = 0; i0 < DIN_; i0 += 4) {
        const float w0 = wp[0 * DOUT_];
        const float w1 = wp[1 * DOUT_];
        const float w2 = wp[2 * DOUT_];
        const float w3 = wp[3 * DOUT_];
        wp += 4 * DOUT_;
#pragma unroll
        for (int b = 0; b < B_; ++b) {
            const float4 xv = *(const float4*)&xp[(size_t)b * S_ * DIN_ + i0];
            acc[b] += xv.x * w0;
            acc[b] += xv.y * w1;
            acc[b] += xv.z * w2;
            acc[b] += xv.w * w3;
        }
    }

#pragma unroll
    for (int b = 0; b < B_; ++b) {
        u_hat[(((size_t)b * C_ + c) * S_ + s) * DOUT_ + lane] = acc[b];
        atomicAdd(&s_acc0[((size_t)b * C_ + c) * DOUT_ + lane], acc[b] * 0.0625f);
    }
}

// squash: v = s * n/(1+n^2), n = ||s||.  One wave per (b,c) row of 64. fp32 out.
__global__ __launch_bounds__(64) void squash_k(
    const float* __restrict__ s_in, float* __restrict__ dst) {
    const int lane = threadIdx.x;
    const int idx  = blockIdx.x;               // b*C + c
    const float val = s_in[idx * DOUT_ + lane];
    float ss = val * val;
#pragma unroll
    for (int off = 32; off; off >>= 1) ss += __shfl_xor(ss, off);
    const float n = sqrtf(ss);
    dst[idx * DOUT_ + lane] = val * (n / (1.f + ss));
}

// One fused pass per routing iteration:
//   a[c]   = dot_o(u_hat[b,c,s,:], v[b,c,:])        (agreement)
//   b_new  = (read_b ? b_old : 0) + a               (cumulative logits)
//   c_ij   = softmax_c(b_new)
//   s_acc += c_ij * u_hat                           (next s_j)
// Wave handles 4 s values for one b; lane = o (DOUT == wavefront size).
__global__ __launch_bounds__(256) void routing_pass(
    const float* __restrict__ u_hat, const float* __restrict__ v_in,
    float* __restrict__ b_io, float* __restrict__ s_acc, int read_b) {
    const int lane  = threadIdx.x & 63;
    const int wave  = threadIdx.x >> 6;
    const int b     = blockIdx.x >> 5;
    const int chunk = blockIdx.x & 31;

    float vl[C_];
#pragma unroll
    for (int c = 0; c < C_; ++c) vl[c] = v_in[((size_t)b * C_ + c) * DOUT_ + lane];

    float acc[C_];
#pragma unroll
    for (int c = 0; c < C_; ++c) acc[c] = 0.f;

    for (int i = 0; i < 4; ++i) {
        const int s = chunk * 16 + wave * 4 + i;
        float u[C_], a[C_];
#pragma unroll
        for (int c = 0; c < C_; ++c)
            u[c] = u_hat[(((size_t)b * C_ + c) * S_ + s) * DOUT_ + lane];
#pragma unroll
        for (int c = 0; c < C_; ++c) a[c] = u[c] * vl[c];
        // 16 independent wave reductions (butterfly -> every lane has full sum)
#pragma unroll
        for (int off = 32; off; off >>= 1) {
#pragma unroll
            for (int c = 0; c < C_; ++c) a[c] += __shfl_xor(a[c], off);
        }
        if (read_b) {
#pragma unroll
            for (int c = 0; c < C_; ++c)
                a[c] += b_io[((size_t)b * C_ + c) * S_ + s];
        }
        if (lane == 0) {
#pragma unroll
            for (int c = 0; c < C_; ++c)
                b_io[((size_t)b * C_ + c) * S_ + s] = a[c];
        }
        // softmax over c
        float mx = a[0];
#pragma unroll
        for (int c = 1; c < C_; ++c) mx = fmaxf(mx, a[c]);
        float sum = 0.f;
#pragma unroll
        for (int c = 0; c < C_; ++c) { a[c] = __expf(a[c] - mx); sum += a[c]; }
        const float inv = 1.f / sum;
#pragma unroll
        for (int c = 0; c < C_; ++c) acc[c] += a[c] * inv * u[c];
    }
#pragma unroll
    for (int c = 0; c < C_; ++c)
        atomicAdd(&s_acc[((size_t)b * C_ + c) * DOUT_ + lane], acc[c]);
}

extern "C" void kernel_launch(void* const* d_in, const int* in_sizes, int n_in,
                              void* d_out, int out_size, void* d_ws, size_t ws_size,
                              hipStream_t stream) {
    const float* x = (const float*)d_in[0];
    const float* W = (const float*)d_in[1];

    float* u_hat  = (float*)d_ws;                              // 16,777,216 f (64 MB)
    float* b_buf  = u_hat + (size_t)B_ * C_ * S_ * DOUT_;      //    262,144 f
    float* s_acc0 = b_buf + (size_t)B_ * C_ * S_;              //     32,768 f each
    float* s_acc1 = s_acc0 + B_ * C_ * DOUT_;
    float* s_acc2 = s_acc1 + B_ * C_ * DOUT_;
    float* v0     = s_acc2 + B_ * C_ * DOUT_;
    float* v1     = v0 + B_ * C_ * DOUT_;

    hipMemsetAsync(s_acc0, 0, (size_t)3 * B_ * C_ * DOUT_ * sizeof(float), stream);

    gemm_uhat<<<S_ * 4, 256, 0, stream>>>(x, W, u_hat, s_acc0);
    squash_k<<<B_ * C_, 64, 0, stream>>>(s_acc0, v0);
    routing_pass<<<B_ * 32, 256, 0, stream>>>(u_hat, v0, b_buf, s_acc1, 0);
    squash_k<<<B_ * C_, 64, 0, stream>>>(s_acc1, v1);
    routing_pass<<<B_ * 32, 256, 0, stream>>>(u_hat, v1, b_buf, s_acc2, 1);
    squash_k<<<B_ * C_, 64, 0, stream>>>(s_acc2, (float*)d_out);
}

// Round 4
// 786.432 us; speedup vs baseline: 1.8360x; 1.8360x over previous
//
#include <hip/hip_runtime.h>
#include <hip/hip_bf16.h>

#define B_    32
#define S_    512
#define C_    16
#define DIN_  256
#define DOUT_ 64

typedef __bf16 bf16x8 __attribute__((ext_vector_type(8)));
typedef float  f32x16 __attribute__((ext_vector_type(16)));

// Split fp32 -> bf16 hi + bf16 lo (lo = RNE(f - float(hi))); hi*hi + hi*lo + lo*hi
// reproduces the fp32 product to ~2^-17 relative.
__device__ inline void split2(float f, __bf16& hi, __bf16& lo) {
    hi = (__bf16)f;
    lo = (__bf16)(f - (float)hi);
}

// u_hat[b,c,s,o] = sum_i x[b,s,i] * W[c,s,i,o]  via MFMA 32x32x16 (split-bf16, 3 mfma/k-block).
// One wave per (c,s): A = x[0:32, s, :] (m=b), B = W[c,s,:,:] (n=o, two 32-col halves).
// All loads are lane-varying (A: m = lane&31 selects row; B: n = lane&31) -- no
// wave-uniform-address scalarization, no scratch (R3's 128MiB WRITE_SIZE spill signature).
// Epilogue fuses routing iter-0: s0[b,c,o] += u_hat/16 (softmax of zeros = 1/C).
__global__ __launch_bounds__(256) void gemm_uhat(
    const float* __restrict__ x, const float* __restrict__ W,
    float* __restrict__ u_hat, float* __restrict__ s_acc0) {
    const int lane = threadIdx.x & 63;
    const int wid  = threadIdx.x >> 6;
    const int s    = blockIdx.x >> 2;                 // 4 blocks per s
    const int c    = ((blockIdx.x & 3) << 2) + wid;   // 4 waves = 4 capsules, same s -> x L1 reuse
    const int m    = lane & 31;                       // A row (b) / B col (o)
    const int kh   = lane >> 5;                       // k-half: k = kh*8 + j

    const float* xp = x + ((size_t)m * S_ + s) * DIN_ + kh * 8;
    const float* wp = W + (((size_t)c * S_ + s) * DIN_ + kh * 8) * DOUT_ + m;

    f32x16 acc0, acc1;
#pragma unroll
    for (int r = 0; r < 16; ++r) { acc0[r] = 0.f; acc1[r] = 0.f; }

#pragma unroll 1
    for (int kb = 0; kb < DIN_ / 16; ++kb) {
        const float4 a0 = *(const float4*)(xp);
        const float4 a1 = *(const float4*)(xp + 4);
        xp += 16;
        float wa[8], wb[8];
#pragma unroll
        for (int j = 0; j < 8; ++j) {
            wa[j] = wp[j * DOUT_];         // W[.., kh*8+j, m]
            wb[j] = wp[j * DOUT_ + 32];    // W[.., kh*8+j, m+32]
        }
        wp += 16 * DOUT_;

        const float af[8] = {a0.x, a0.y, a0.z, a0.w, a1.x, a1.y, a1.z, a1.w};
        bf16x8 ahi, alo, b0hi, b0lo, b1hi, b1lo;
#pragma unroll
        for (int j = 0; j < 8; ++j) {
            __bf16 h, l;
            split2(af[j], h, l); ahi[j] = h; alo[j] = l;
            split2(wa[j], h, l); b0hi[j] = h; b0lo[j] = l;
            split2(wb[j], h, l); b1hi[j] = h; b1lo[j] = l;
        }
        acc0 = __builtin_amdgcn_mfma_f32_32x32x16_bf16(ahi, b0hi, acc0, 0, 0, 0);
        acc0 = __builtin_amdgcn_mfma_f32_32x32x16_bf16(ahi, b0lo, acc0, 0, 0, 0);
        acc0 = __builtin_amdgcn_mfma_f32_32x32x16_bf16(alo, b0hi, acc0, 0, 0, 0);
        acc1 = __builtin_amdgcn_mfma_f32_32x32x16_bf16(ahi, b1hi, acc1, 0, 0, 0);
        acc1 = __builtin_amdgcn_mfma_f32_32x32x16_bf16(ahi, b1lo, acc1, 0, 0, 0);
        acc1 = __builtin_amdgcn_mfma_f32_32x32x16_bf16(alo, b1hi, acc1, 0, 0, 0);
    }

    // C/D layout (HW-verified m74/m101): col(o) = lane&31, row(b) = (r&3) + 8*(r>>2) + 4*kh
#pragma unroll
    for (int r = 0; r < 16; ++r) {
        const int b = (r & 3) + 8 * (r >> 2) + 4 * kh;
        const size_t base = (((size_t)b * C_ + c) * S_ + s) * DOUT_;
        u_hat[base + m]      = acc0[r];
        u_hat[base + m + 32] = acc1[r];
        const size_t sb = ((size_t)b * C_ + c) * DOUT_;
        atomicAdd(&s_acc0[sb + m],      acc0[r] * 0.0625f);
        atomicAdd(&s_acc0[sb + m + 32], acc1[r] * 0.0625f);
    }
}

// squash: v = s * n/(1+n^2), n = ||s||.  One wave per (b,c) row of 64. fp32 out.
__global__ __launch_bounds__(64) void squash_k(
    const float* __restrict__ s_in, float* __restrict__ dst) {
    const int lane = threadIdx.x;
    const int idx  = blockIdx.x;               // b*C + c
    const float val = s_in[idx * DOUT_ + lane];
    float ss = val * val;
#pragma unroll
    for (int off = 32; off; off >>= 1) ss += __shfl_xor(ss, off);
    const float n = sqrtf(ss);
    dst[idx * DOUT_ + lane] = val * (n / (1.f + ss));
}

// One fused pass per routing iteration:
//   a[c]   = dot_o(u_hat[b,c,s,:], v[b,c,:]) (+ b_old)   -> b_new (stored [b,s,c])
//   c_ij   = softmax_c(b_new);  s_acc += c_ij * u_hat
// Wave handles 4 s values for one b; lane = o. u_hat rows are RELOADED after the
// softmax (L1-hit) instead of kept live -> peak ~56 VGPRs, no spill.
__global__ __launch_bounds__(256) void routing_pass(
    const float* __restrict__ u_hat, const float* __restrict__ v_in,
    float* __restrict__ b_io, float* __restrict__ s_acc, int read_b) {
    const int lane  = threadIdx.x & 63;
    const int wave  = threadIdx.x >> 6;
    const int b     = blockIdx.x >> 5;
    const int chunk = blockIdx.x & 31;

    float vl[C_];
#pragma unroll
    for (int c = 0; c < C_; ++c) vl[c] = v_in[((size_t)b * C_ + c) * DOUT_ + lane];

    float acc[C_];
#pragma unroll
    for (int c = 0; c < C_; ++c) acc[c] = 0.f;

#pragma unroll 1
    for (int i = 0; i < 4; ++i) {
        const int s = chunk * 16 + wave * 4 + i;
        const size_t ub = (((size_t)b * C_) * S_ + s) * DOUT_ + lane;  // + c*S_*DOUT_
        float a[C_];
#pragma unroll
        for (int c = 0; c < C_; ++c)
            a[c] = u_hat[ub + (size_t)c * S_ * DOUT_] * vl[c];
        // 16 independent wave reductions (butterfly -> every lane has full sum)
#pragma unroll
        for (int off = 32; off; off >>= 1) {
#pragma unroll
            for (int c = 0; c < C_; ++c) a[c] += __shfl_xor(a[c], off);
        }
        if (read_b) {
#pragma unroll
            for (int c = 0; c < C_; ++c)
                a[c] += b_io[((size_t)b * S_ + s) * C_ + c];
        }
        if (lane == 0) {
#pragma unroll
            for (int c = 0; c < C_; ++c)
                b_io[((size_t)b * S_ + s) * C_ + c] = a[c];
        }
        // softmax over c
        float mx = a[0];
#pragma unroll
        for (int c = 1; c < C_; ++c) mx = fmaxf(mx, a[c]);
        float sum = 0.f;
#pragma unroll
        for (int c = 0; c < C_; ++c) { a[c] = __expf(a[c] - mx); sum += a[c]; }
        const float inv = 1.f / sum;
#pragma unroll
        for (int c = 0; c < C_; ++c)
            acc[c] += a[c] * inv * u_hat[ub + (size_t)c * S_ * DOUT_];
    }
#pragma unroll
    for (int c = 0; c < C_; ++c)
        atomicAdd(&s_acc[((size_t)b * C_ + c) * DOUT_ + lane], acc[c]);
}

extern "C" void kernel_launch(void* const* d_in, const int* in_sizes, int n_in,
                              void* d_out, int out_size, void* d_ws, size_t ws_size,
                              hipStream_t stream) {
    const float* x = (const float*)d_in[0];
    const float* W = (const float*)d_in[1];

    float* u_hat  = (float*)d_ws;                              // 16,777,216 f (64 MB)
    float* b_buf  = u_hat + (size_t)B_ * C_ * S_ * DOUT_;      //    262,144 f  [b,s,c]
    float* s_acc0 = b_buf + (size_t)B_ * C_ * S_;              //     32,768 f each
    float* s_acc1 = s_acc0 + B_ * C_ * DOUT_;
    float* s_acc2 = s_acc1 + B_ * C_ * DOUT_;
    float* v0     = s_acc2 + B_ * C_ * DOUT_;
    float* v1     = v0 + B_ * C_ * DOUT_;

    hipMemsetAsync(s_acc0, 0, (size_t)3 * B_ * C_ * DOUT_ * sizeof(float), stream);

    gemm_uhat<<<S_ * 4, 256, 0, stream>>>(x, W, u_hat, s_acc0);
    squash_k<<<B_ * C_, 64, 0, stream>>>(s_acc0, v0);
    routing_pass<<<B_ * 32, 256, 0, stream>>>(u_hat, v0, b_buf, s_acc1, 0);
    squash_k<<<B_ * C_, 64, 0, stream>>>(s_acc1, v1);
    routing_pass<<<B_ * 32, 256, 0, stream>>>(u_hat, v1, b_buf, s_acc2, 1);
    squash_k<<<B_ * C_, 64, 0, stream>>>(s_acc2, (float*)d_out);
}